// Round 19
// baseline (661.601 us; speedup 1.0000x reference)
//
#include <hip/hip_runtime.h>
#include <hip/hip_bf16.h>
#include <math.h>

typedef unsigned short u16;
typedef __attribute__((ext_vector_type(8))) short bf16x8;
typedef __attribute__((ext_vector_type(8))) unsigned short u16x8;
typedef __attribute__((ext_vector_type(4))) float f32x4;

#define MFMA_BF16 __builtin_amdgcn_mfma_f32_16x16x32_bf16

__device__ __forceinline__ u16 f2bf(float f){
  union { float f; unsigned u; } v; v.f = f;
  unsigned r = v.u + 0x7FFFu + ((v.u >> 16) & 1u);
  return (u16)(r >> 16);
}

// sigmoid-form GELU: x * sigma(1.702 x), with single-instruction v_rcp_f32
// (NOT an fp32 '/' -- that emits IEEE div_scale/fmas/fixup, the R17 +170us bug).
// ~6 VALU ops vs erff's ~15. |err| vs exact GELU <= ~0.02 (decorrelates through FC2).
__device__ __forceinline__ float gelu_sig(float x){
  float e = __expf(-1.702f * x);
  return x * __builtin_amdgcn_rcpf(1.f + e);
}

__device__ __forceinline__ void gll16(const void* g, void* l){
  __builtin_amdgcn_global_load_lds(
      (const __attribute__((address_space(1))) unsigned int*)g,
      (__attribute__((address_space(3))) unsigned int*)l, 16, 0, 0);
}

__global__ void k_concat_bias(const float* __restrict__ a, const float* __restrict__ b,
                              const float* __restrict__ c, float* __restrict__ o){
  int i = threadIdx.x;  // 768 threads
  o[i] = i < 256 ? a[i] : (i < 512 ? b[i-256] : c[i-512]);
}

// ---- weights -> MFMA-fragment-major: F[n16][ks][lane][8] = W[k][n],
// k = ks*32 + (lane>>4)*8 + j, n = n16*16 + (lane&15)
__global__ __launch_bounds__(256) void k_wfrag(const float* __restrict__ W, u16* __restrict__ F,
                                               int K, int N){
  int idx = blockIdx.x*256 + threadIdx.x;
  int nks = K >> 5;
  int per_n16 = nks << 9;
  int n16 = idx / per_n16; int rem = idx - n16*per_n16;
  int ks = rem >> 9, l8 = rem & 511, lane = l8 >> 3, j = l8 & 7;
  int k = ks*32 + ((lane >> 4) << 3) + j;
  int n = (n16 << 4) + (lane & 15);
  F[idx] = f2bf(W[(size_t)k*N + n]);
}

// ---- QKV weights fragment-major (per head) ----
__global__ __launch_bounds__(256) void k_fragw(const float* __restrict__ wq, const float* __restrict__ wk,
                                               const float* __restrict__ wv, u16* __restrict__ fragW){
  int idx = blockIdx.x*256 + threadIdx.x;    // 3*65536
  int j = idx & 7, lane = (idx >> 3) & 63, nj = (idx >> 9) & 1;
  int ks = (idx >> 10) & 7, h = (idx >> 13) & 7, type = idx >> 16;
  const float* w = type == 0 ? wq : (type == 1 ? wk : wv);
  int k = ks*32 + 8*(lane >> 4) + j;
  int n = h*32 + nj*16 + (lane & 15);
  fragW[idx] = f2bf(w[(size_t)k*256 + n]);
}

// ---- fused rel-pos bias + shift mask, fragment layout: fb2[cls][h][m][lr][nj] ----
__global__ __launch_bounds__(256) void k_bias(const float* __restrict__ btab, float* __restrict__ fb){
  int idx = blockIdx.x*256 + threadIdx.x;   // 4*8*64*64 = 131072
  int nj = idx & 3, lr = (idx >> 2) & 15, m = (idx >> 6) & 63, hh = (idx >> 12) & 7, cls = idx >> 15;
  int n = nj*16 + lr;
  int r1=m>>3, c1=m&7, r2=n>>3, c2=n&7;
  float bv = btab[((r1-r2+7)*15 + (c1-c2+7))*8 + hh];
  int whe = cls>>1, wwe = cls&1;
  int a1 = (whe ? (r1<4?1:2) : 0)*3 + (wwe ? (c1<4?1:2) : 0);
  int a2 = (whe ? (r2<4?1:2) : 0)*3 + (wwe ? (c2<4?1:2) : 0);
  fb[idx] = bv + ((a1!=a2) ? -100.f : 0.f);
}

// ======== FUSED LN1 + QKV + windowed attention + O-proj + residual + LN2 ========
// One block per window (2048). 16 waves = 8 heads x 2 token-halves.
__global__ __launch_bounds__(1024) void k_fattn(const float* __restrict__ hidden,
    const float* __restrict__ g1, const float* __restrict__ b1f,
    const u16* __restrict__ fragW, const float* __restrict__ bqkv,
    const float* __restrict__ fb, const u16* __restrict__ woF,
    const float* __restrict__ bo, const float* __restrict__ g2,
    const float* __restrict__ b2v,
    float* __restrict__ hs_out, u16* __restrict__ y2)
{
  __shared__ __align__(16) u16 lds[75776];   // 151552 B
  int tid = threadIdx.x, lane = tid & 63, wid = tid >> 6;
  int lg = lane >> 4, lr = lane & 15;
  int h = wid >> 1, s = wid & 1;
  int gw = blockIdx.x;
  int bi = gw >> 6, win = gw & 63, wh = win >> 3, wwi = win & 7;

  // ---- Phase 1: LN1 + cyclic-shift gather -> xb (chunk-XOR swizzled) ----
  {
    int t = wid*4 + (lane >> 4);           // token 0..63 (16 lanes/token)
    int j = lane & 15;                     // 16-channel slice
    int hh_ = (wh*8 + (t >> 3) + 4) & 63;
    int ww_ = (wwi*8 + (t & 7) + 4) & 63;
    const float4* row = (const float4*)(hidden + ((size_t)bi*4096 + hh_*64 + ww_)*256) + j*4;
    float4 v[4]; float sm = 0.f, sq = 0.f;
#pragma unroll
    for (int i=0;i<4;i++){
      v[i] = row[i];
      sm += v[i].x+v[i].y+v[i].z+v[i].w;
      sq += v[i].x*v[i].x+v[i].y*v[i].y+v[i].z*v[i].z+v[i].w*v[i].w;
    }
    sm += __shfl_xor(sm,1); sq += __shfl_xor(sq,1);
    sm += __shfl_xor(sm,2); sq += __shfl_xor(sq,2);
    sm += __shfl_xor(sm,4); sq += __shfl_xor(sq,4);
    sm += __shfl_xor(sm,8); sq += __shfl_xor(sq,8);
    float mean = sm*(1.f/256.f);
    float inv = rsqrtf(sq*(1.f/256.f) - mean*mean + 1e-5f);
    const float4* gg = (const float4*)g1 + j*4;
    const float4* bb = (const float4*)b1f + j*4;
#pragma unroll
    for (int i2=0;i2<2;i2++){
      float4 a0=v[2*i2], a1=v[2*i2+1];
      float4 g0=gg[2*i2], g1_=gg[2*i2+1];
      float4 b0=bb[2*i2], b1_=bb[2*i2+1];
      u16x8 pk;
      pk[0]=f2bf((a0.x-mean)*inv*g0.x+b0.x); pk[1]=f2bf((a0.y-mean)*inv*g0.y+b0.y);
      pk[2]=f2bf((a0.z-mean)*inv*g0.z+b0.z); pk[3]=f2bf((a0.w-mean)*inv*g0.w+b0.w);
      pk[4]=f2bf((a1.x-mean)*inv*g1_.x+b1_.x); pk[5]=f2bf((a1.y-mean)*inv*g1_.y+b1_.y);
      pk[6]=f2bf((a1.z-mean)*inv*g1_.z+b1_.z); pk[7]=f2bf((a1.w-mean)*inv*g1_.w+b1_.w);
      int c = (j*2 + i2) ^ (t & 7);
      *(u16x8*)(&lds[t*256 + c*8]) = pk;
    }
  }
  __syncthreads();

  // ---- Phase 2: mini-GEMM q/k/v for head h, token half s (fragW from L2) ----
  f32x4 qa[2][2]={}, ka[2][2]={}, va[2][2]={};
  __builtin_amdgcn_s_setprio(1);
#pragma unroll
  for (int ks=0; ks<8; ks++){
    bf16x8 af[2];
#pragma unroll
    for (int mi=0;mi<2;mi++){
      int tok = 32*s + mi*16 + lr;
      af[mi] = *(const bf16x8*)(&lds[tok*256 + (((ks*4+lg) ^ (tok&7))*8)]);
    }
    const u16* fq = fragW + ((((size_t)h)*8 + ks)*2)*512 + lane*8;
#pragma unroll
    for (int nj=0;nj<2;nj++){
      bf16x8 bq_ = *(const bf16x8*)(fq + nj*512);
      bf16x8 bk_ = *(const bf16x8*)(fq + 65536 + nj*512);
      bf16x8 bv_ = *(const bf16x8*)(fq + 131072 + nj*512);
#pragma unroll
      for (int mi=0;mi<2;mi++){
        qa[mi][nj] = MFMA_BF16(af[mi], bq_, qa[mi][nj], 0,0,0);
        ka[mi][nj] = MFMA_BF16(af[mi], bk_, ka[mi][nj], 0,0,0);
        va[mi][nj] = MFMA_BF16(af[mi], bv_, va[mi][nj], 0,0,0);
      }
    }
  }
  __builtin_amdgcn_s_setprio(0);

  // ---- Phase 3: q/k/v -> per-head arena (each wave writes its token half) ----
  u16* hb  = &lds[16384 + h*7424];
  u16* k_h = hb;                    // [64][40]
  u16* v_h = hb + 2560;             // [32 dims][72]
  u16* q_s = hb + 4864 + s*1280;    // [32][40]
  const float scale = 0.1767766952966369f; // 32^-0.5
#pragma unroll
  for (int mi=0;mi<2;mi++)
#pragma unroll
  for (int nj=0;nj<2;nj++){
    int dim = nj*16+lr;
    float bq_ = bqkv[h*32+dim], bk_ = bqkv[256+h*32+dim], bv_ = bqkv[512+h*32+dim];
#pragma unroll
    for (int r=0;r<4;r++){
      int tokl = mi*16+4*lg+r;            // local 0..31
      q_s[tokl*40+dim] = f2bf((qa[mi][nj][r]+bq_)*scale);
      k_h[(32*s+tokl)*40+dim] = f2bf(ka[mi][nj][r]+bk_);
    }
    ushort4 vp;
    vp.x = f2bf(va[mi][nj][0]+bv_); vp.y = f2bf(va[mi][nj][1]+bv_);
    vp.z = f2bf(va[mi][nj][2]+bv_); vp.w = f2bf(va[mi][nj][3]+bv_);
    *(ushort4*)(&v_h[dim*72 + 32*s + mi*16 + 4*lg]) = vp;
  }
  __syncthreads();   // k_h/v_h halves from both waves visible

  // ---- Phase 4: QK^T (32 q-rows x 64 k) + bias/mask + softmax ----
  bf16x8 qf[2], kf[4];
#pragma unroll
  for (int i=0;i<2;i++)
    qf[i] = *(const bf16x8*)(&q_s[(i*16+lr)*40 + 8*lg]);
#pragma unroll
  for (int i=0;i<4;i++)
    kf[i] = *(const bf16x8*)(&k_h[(i*16+lr)*40 + 8*lg]);
  f32x4 acc[2][4] = {};
#pragma unroll
  for (int mi=0;mi<2;mi++)
#pragma unroll
  for (int nj=0;nj<4;nj++)
    acc[mi][nj] = MFMA_BF16(qf[mi], kf[nj], acc[mi][nj], 0,0,0);

  int cls = ((wh==7) ? 2 : 0) | ((wwi==7) ? 1 : 0);
  const float4* fb4 = (const float4*)(fb + (((size_t)cls*8 + h) << 12));
#pragma unroll
  for (int mi=0;mi<2;mi++)
#pragma unroll
  for (int r=0;r<4;r++){
    int m = 32*s + mi*16 + 4*lg + r;
    float4 bv4 = fb4[m*16 + lr];
#pragma unroll
    for (int nj=0;nj<4;nj++)
      acc[mi][nj][r] += bv4[nj];
  }
#pragma unroll
  for (int mi=0;mi<2;mi++)
#pragma unroll
  for (int r=0;r<4;r++){
    float mx = fmaxf(fmaxf(acc[mi][0][r], acc[mi][1][r]), fmaxf(acc[mi][2][r], acc[mi][3][r]));
    for (int off=1; off<16; off<<=1) mx = fmaxf(mx, __shfl_xor(mx, off));
    float sum = 0.f;
#pragma unroll
    for (int nj=0;nj<4;nj++){ float e = __expf(acc[mi][nj][r]-mx); acc[mi][nj][r]=e; sum+=e; }
    for (int off=1; off<16; off<<=1) sum += __shfl_xor(sum, off);
    float inv = 1.f/sum;
#pragma unroll
    for (int nj=0;nj<4;nj++) acc[mi][nj][r] *= inv;
  }

  // P overwrites k/q regions read by partner's QK^T; also all phase-2 xb reads
  // must be done before the out-tile overwrites xb below -> block sync.
  __syncthreads();

  u16* P_s = s ? hb : (hb + 4864);   // [32][72], wave-private
#pragma unroll
  for (int mi=0;mi<2;mi++)
#pragma unroll
  for (int nj=0;nj<4;nj++)
#pragma unroll
  for (int r=0;r<4;r++)
    P_s[(mi*16+4*lg+r)*72 + nj*16 + lr] = f2bf(acc[mi][nj][r]);

  // ---- Phase 5: PV (own 32 rows x full V) ----
  f32x4 acc2[2][2] = {};
#pragma unroll
  for (int ks=0; ks<2; ks++){
    bf16x8 vf0 = *(const bf16x8*)(&v_h[(lr)*72 + ks*32 + 8*lg]);
    bf16x8 vf1 = *(const bf16x8*)(&v_h[(16+lr)*72 + ks*32 + 8*lg]);
#pragma unroll
    for (int mi=0;mi<2;mi++){
      bf16x8 pf = *(const bf16x8*)(&P_s[(mi*16+lr)*72 + ks*32 + 8*lg]);
      acc2[mi][0] = MFMA_BF16(pf, vf0, acc2[mi][0], 0,0,0);
      acc2[mi][1] = MFMA_BF16(pf, vf1, acc2[mi][1], 0,0,0);
    }
  }

  // ---- Phase 6: attn-out tile -> xb (same chunk-XOR swizzle) ----
#pragma unroll
  for (int mi=0;mi<2;mi++)
#pragma unroll
  for (int nt=0;nt<2;nt++)
#pragma unroll
  for (int r=0;r<4;r++){
    int row = 32*s + mi*16 + 4*lg + r;
    int chunk = (4*h + 2*nt + (lr>>3)) ^ (row & 7);
    lds[row*256 + chunk*8 + (lr&7)] = f2bf(acc2[mi][nt][r]);
  }
  __syncthreads();   // full 64x256 out tile visible; arenas now dead

  // ---- Phase 7: O-proj mini-GEMM: rows 32s..+31, cols 32h..+31, K=256 ----
  f32x4 po[2][2] = {};
  __builtin_amdgcn_s_setprio(1);
#pragma unroll
  for (int ks=0; ks<8; ks++){
    bf16x8 af2[2];
#pragma unroll
    for (int mi=0;mi<2;mi++){
      int row = 32*s + mi*16 + lr;
      af2[mi] = *(const bf16x8*)(&lds[row*256 + (((ks*4+lg) ^ (row&7))*8)]);
    }
#pragma unroll
    for (int nj=0;nj<2;nj++){
      bf16x8 bw = *(const bf16x8*)(woF + (((size_t)(2*h+nj))*8 + ks)*512 + lane*8);
#pragma unroll
      for (int mi=0;mi<2;mi++)
        po[mi][nj] = MFMA_BF16(af2[mi], bw, po[mi][nj], 0,0,0);
    }
  }
  __builtin_amdgcn_s_setprio(0);

  // ---- Phase 8: +bo, window-reverse residual, hs -> d_out, LN2 partials ----
  float* part_s = (float*)&lds[16384];          // [64][8]
  float* part_q = (float*)&lds[16384 + 1024];   // [64][8]
  float bov[2], g2v[2], b2vv[2];
#pragma unroll
  for (int nj=0;nj<2;nj++){
    int n = 32*h + nj*16 + lr;
    bov[nj] = bo[n]; g2v[nj] = g2[n]; b2vv[nj] = b2v[n];
  }
#pragma unroll
  for (int mi=0;mi<2;mi++)
#pragma unroll
  for (int r=0;r<4;r++){
    int p = 32*s + mi*16 + 4*lg + r;       // row in window
    int hh_ = (wh*8 + (p >> 3) + 4) & 63;
    int ww_ = (wwi*8 + (p & 7) + 4) & 63;
    size_t base = ((size_t)bi*4096 + hh_*64 + ww_)*256;
    float ls = 0.f, lq = 0.f;
#pragma unroll
    for (int nj=0;nj<2;nj++){
      int n = 32*h + nj*16 + lr;
      float v = po[mi][nj][r] + bov[nj] + hidden[base + n];
      hs_out[base + n] = v;
      po[mi][nj][r] = v;
      ls += v; lq += v*v;
    }
    ls += __shfl_xor(ls,1); lq += __shfl_xor(lq,1);
    ls += __shfl_xor(ls,2); lq += __shfl_xor(lq,2);
    ls += __shfl_xor(ls,4); lq += __shfl_xor(lq,4);
    ls += __shfl_xor(ls,8); lq += __shfl_xor(lq,8);
    if (lr == 0){ part_s[p*8 + h] = ls; part_q[p*8 + h] = lq; }
  }
  __syncthreads();

  // ---- Phase 9: LN2 finalize -> y2 bf16 (token order) ----
#pragma unroll
  for (int mi=0;mi<2;mi++)
#pragma unroll
  for (int r=0;r<4;r++){
    int p = 32*s + mi*16 + 4*lg + r;
    int hh_ = (wh*8 + (p >> 3) + 4) & 63;
    int ww_ = (wwi*8 + (p & 7) + 4) & 63;
    size_t base = ((size_t)bi*4096 + hh_*64 + ww_)*256;
    float sum = 0.f, sqq = 0.f;
#pragma unroll
    for (int hh2=0; hh2<8; hh2++){ sum += part_s[p*8 + hh2]; sqq += part_q[p*8 + hh2]; }
    float mean = sum*(1.f/256.f);
    float inv = rsqrtf(sqq*(1.f/256.f) - mean*mean + 1e-5f);
#pragma unroll
    for (int nj=0;nj<2;nj++){
      int n = 32*h + nj*16 + lr;
      y2[base + n] = f2bf((po[mi][nj][r]-mean)*inv*g2v[nj] + b2vv[nj]);
    }
  }
}

// ======== FUSED MLP: out = hs + GELU(y2 @ w1 + b1) @ w2 + b2, K-split over d_ff ========
// R13 structure (proven 331us). Single change: sigmoid-GELU with v_rcp_f32
// (6 VALU ops; erff ~15; R17's tanh-form fp32 '/' was +170us).
__global__ __launch_bounds__(512) void k_mlp(const u16* __restrict__ y2ln,
    const u16* __restrict__ w1F, const u16* __restrict__ w2F,
    const float* __restrict__ b1, const float* __restrict__ b2,
    float* __restrict__ io)
{
  __shared__ __align__(16) u16 lds[32768];   // xb [0,16384) + t [16384,32768)
  int tid = threadIdx.x, lane = tid & 63, wid = tid >> 6;
  int lg = lane >> 4, lr = lane & 15;
  int wr_ = wid >> 2, wc_ = wid & 3;
  int m0 = blockIdx.x*64;

  // stage x = y2ln rows m0..+64 into xb, chunk-XOR swizzled via pre-swizzled source
  {
    int row_lo = tid >> 5;           // 0..15
    int ch = tid & 31;               // 16B chunk within 512B row
#pragma unroll
    for (int i=0;i<4;i++){
      int row = i*16 + row_lo;
      int sch = ch ^ (row & 7);
      gll16(y2ln + (size_t)(m0+row)*256 + sch*8, &lds[i*4096 + tid*8]);
    }
  }
  asm volatile("s_waitcnt vmcnt(0)" ::: "memory");
  __syncthreads();

  u16* xt = &lds[16384];
  f32x4 accY[2][4] = {};
  float b2v[4];
#pragma unroll
  for (int nj=0;nj<4;nj++) b2v[nj] = b2[wc_*64 + nj*16 + lr];

  for (int c = 0; c < 4; c++){
    // ---- FC1: t_c[64][wid*32..+32] = x @ w1[:, c*256 + wid*32 ..], K=256 ----
    f32x4 acc1[4][2] = {};
    __builtin_amdgcn_s_setprio(1);
#pragma unroll
    for (int ks=0; ks<8; ks++){
      bf16x8 af[4];
#pragma unroll
      for (int mi=0;mi<4;mi++){
        int row = mi*16 + lr;
        af[mi] = *(const bf16x8*)(&lds[row*256 + (((ks*4+lg) ^ (row&7))<<3)]);
      }
#pragma unroll
      for (int nj=0;nj<2;nj++){
        bf16x8 bw = *(const bf16x8*)(w1F + ((((size_t)(c*16 + wid*2 + nj))*8 + ks)<<9) + lane*8);
#pragma unroll
        for (int mi=0;mi<4;mi++)
          acc1[mi][nj] = MFMA_BF16(af[mi], bw, acc1[mi][nj], 0,0,0);
      }
    }
    __builtin_amdgcn_s_setprio(0);
    __syncthreads();   // previous FC2's t-reads complete before overwrite
    // GELU + write t (swizzled)
#pragma unroll
    for (int mi=0;mi<4;mi++)
#pragma unroll
    for (int nj=0;nj<2;nj++){
      float b1v = b1[c*256 + wid*32 + nj*16 + lr];
#pragma unroll
      for (int r=0;r<4;r++){
        int row = mi*16 + 4*lg + r;
        int col = wid*32 + nj*16 + lr;
        float v = acc1[mi][nj][r] + b1v;
        float gv = gelu_sig(v);
        xt[row*256 + ((((col>>3) ^ (row&7))<<3) | (col&7))] = f2bf(gv);
      }
    }
    __syncthreads();   // t_c fully visible
    // ---- FC2: accY += t_c[32wr_..+32][:] @ w2[c*256..+256][64wc_..+64] ----
    __builtin_amdgcn_s_setprio(1);
#pragma unroll
    for (int ks=0; ks<8; ks++){
      bf16x8 af2[2];
#pragma unroll
      for (int mi=0;mi<2;mi++){
        int row = wr_*32 + mi*16 + lr;
        af2[mi] = *(const bf16x8*)(&xt[row*256 + (((ks*4+lg) ^ (row&7))<<3)]);
      }
#pragma unroll
      for (int nj=0;nj<4;nj++){
        bf16x8 bw = *(const bf16x8*)(w2F + ((((size_t)(wc_*4 + nj))*32 + c*8 + ks)<<9) + lane*8);
#pragma unroll
        for (int mi=0;mi<2;mi++)
          accY[mi][nj] = MFMA_BF16(af2[mi], bw, accY[mi][nj], 0,0,0);
      }
    }
    __builtin_amdgcn_s_setprio(0);
  }

  // ---- epilogue: out = accY + b2 + hs (in place, fp32) ----
#pragma unroll
  for (int mi=0;mi<2;mi++)
#pragma unroll
  for (int nj=0;nj<4;nj++)
#pragma unroll
  for (int r=0;r<4;r++){
    int m = m0 + wr_*32 + mi*16 + 4*lg + r;
    int n = wc_*64 + nj*16 + lr;
    io[(size_t)m*256 + n] = accY[mi][nj][r] + b2v[nj] + io[(size_t)m*256 + n];
  }
}

extern "C" void kernel_launch(void* const* d_in, const int* in_sizes, int n_in,
                              void* d_out, int out_size, void* d_ws, size_t ws_size,
                              hipStream_t stream){
  const float* hidden = (const float*)d_in[0];
  const float* ln1g = (const float*)d_in[1];
  const float* ln1b = (const float*)d_in[2];
  const float* wq   = (const float*)d_in[3];
  const float* bq   = (const float*)d_in[4];
  const float* wk   = (const float*)d_in[5];
  const float* bk   = (const float*)d_in[6];
  const float* wv   = (const float*)d_in[7];
  const float* bv   = (const float*)d_in[8];
  const float* btab = (const float*)d_in[9];
  const float* wo   = (const float*)d_in[10];
  const float* bo   = (const float*)d_in[11];
  const float* ln2g = (const float*)d_in[12];
  const float* ln2b = (const float*)d_in[13];
  const float* w1   = (const float*)d_in[14];
  const float* b1   = (const float*)d_in[15];
  const float* w2   = (const float*)d_in[16];
  const float* b2   = (const float*)d_in[17];
  float* out = (float*)d_out;

  char* ws = (char*)d_ws;
  const size_t MB = 1ull << 20;
  u16* y2ln  = (u16*)(ws + 192*MB);      // LN2 out (64MB)
  u16* fragW = (u16*)(ws + 256*MB);      // QKV weights, fragment-major (384KB)
  u16* woF   = fragW + 196608;           // 16*8*512  = 65536 u16
  u16* w1F   = woF + 65536;              // 64*8*512  = 262144 u16
  u16* w2F   = w1F + 262144;             // 16*32*512 = 262144 u16
  float* bqkv = (float*)(w2F + 262144);
  float* fbias = bqkv + 1024;            // 4*8*64*64 fp32 = 512KB

  // weight prep
  k_fragw<<<768, 256, 0, stream>>>(wq, wk, wv, fragW);
  k_wfrag<<<256, 256, 0, stream>>>(wo, woF, 256, 256);
  k_wfrag<<<1024,256, 0, stream>>>(w1, w1F, 256, 1024);
  k_wfrag<<<1024,256, 0, stream>>>(w2, w2F, 1024, 256);
  k_concat_bias<<<1, 768, 0, stream>>>(bq, bk, bv, bqkv);
  k_bias<<<512, 256, 0, stream>>>(btab, fbias);

  // fused LN1 + shift + QKV + attention + O-proj + residual -> hs (d_out), LN2 -> y2ln
  k_fattn<<<2048, 1024, 0, stream>>>(hidden, ln1g, ln1b, fragW, bqkv, fbias,
                                     woF, bo, ln2g, ln2b, out, y2ln);
  // fused MLP (FC1 + GELU + FC2 + residual), y1 stays in LDS
  k_mlp<<<2048, 512, 0, stream>>>(y2ln, w1F, w2F, b1, b2, out);
}

// Round 20
// 459.063 us; speedup vs baseline: 1.4412x; 1.4412x over previous
//
#include <hip/hip_runtime.h>
#include <hip/hip_bf16.h>
#include <math.h>

typedef unsigned short u16;
typedef __attribute__((ext_vector_type(8))) short bf16x8;
typedef __attribute__((ext_vector_type(8))) unsigned short u16x8;
typedef __attribute__((ext_vector_type(4))) float f32x4;

#define MFMA_BF16 __builtin_amdgcn_mfma_f32_16x16x32_bf16

__device__ __forceinline__ u16 f2bf(float f){
  union { float f; unsigned u; } v; v.f = f;
  unsigned r = v.u + 0x7FFFu + ((v.u >> 16) & 1u);
  return (u16)(r >> 16);
}

__device__ __forceinline__ void gll16(const void* g, void* l){
  __builtin_amdgcn_global_load_lds(
      (const __attribute__((address_space(1))) unsigned int*)g,
      (__attribute__((address_space(3))) unsigned int*)l, 16, 0, 0);
}

__global__ void k_concat_bias(const float* __restrict__ a, const float* __restrict__ b,
                              const float* __restrict__ c, float* __restrict__ o){
  int i = threadIdx.x;  // 768 threads
  o[i] = i < 256 ? a[i] : (i < 512 ? b[i-256] : c[i-512]);
}

// ---- weights -> MFMA-fragment-major: F[n16][ks][lane][8] = W[k][n],
// k = ks*32 + (lane>>4)*8 + j, n = n16*16 + (lane&15)
__global__ __launch_bounds__(256) void k_wfrag(const float* __restrict__ W, u16* __restrict__ F,
                                               int K, int N){
  int idx = blockIdx.x*256 + threadIdx.x;
  int nks = K >> 5;
  int per_n16 = nks << 9;
  int n16 = idx / per_n16; int rem = idx - n16*per_n16;
  int ks = rem >> 9, l8 = rem & 511, lane = l8 >> 3, j = l8 & 7;
  int k = ks*32 + ((lane >> 4) << 3) + j;
  int n = (n16 << 4) + (lane & 15);
  F[idx] = f2bf(W[(size_t)k*N + n]);
}

// ---- QKV weights fragment-major (per head) ----
__global__ __launch_bounds__(256) void k_fragw(const float* __restrict__ wq, const float* __restrict__ wk,
                                               const float* __restrict__ wv, u16* __restrict__ fragW){
  int idx = blockIdx.x*256 + threadIdx.x;    // 3*65536
  int j = idx & 7, lane = (idx >> 3) & 63, nj = (idx >> 9) & 1;
  int ks = (idx >> 10) & 7, h = (idx >> 13) & 7, type = idx >> 16;
  const float* w = type == 0 ? wq : (type == 1 ? wk : wv);
  int k = ks*32 + 8*(lane >> 4) + j;
  int n = h*32 + nj*16 + (lane & 15);
  fragW[idx] = f2bf(w[(size_t)k*256 + n]);
}

// ---- fused rel-pos bias + shift mask, fragment layout: fb2[cls][h][m][lr][nj] ----
__global__ __launch_bounds__(256) void k_bias(const float* __restrict__ btab, float* __restrict__ fb){
  int idx = blockIdx.x*256 + threadIdx.x;   // 4*8*64*64 = 131072
  int nj = idx & 3, lr = (idx >> 2) & 15, m = (idx >> 6) & 63, hh = (idx >> 12) & 7, cls = idx >> 15;
  int n = nj*16 + lr;
  int r1=m>>3, c1=m&7, r2=n>>3, c2=n&7;
  float bv = btab[((r1-r2+7)*15 + (c1-c2+7))*8 + hh];
  int whe = cls>>1, wwe = cls&1;
  int a1 = (whe ? (r1<4?1:2) : 0)*3 + (wwe ? (c1<4?1:2) : 0);
  int a2 = (whe ? (r2<4?1:2) : 0)*3 + (wwe ? (c2<4?1:2) : 0);
  fb[idx] = bv + ((a1!=a2) ? -100.f : 0.f);
}

// ======== FUSED LN1 + QKV + windowed attention + O-proj + residual + LN2 ========
// One block per window (2048). 16 waves = 8 heads x 2 token-halves.
__global__ __launch_bounds__(1024) void k_fattn(const float* __restrict__ hidden,
    const float* __restrict__ g1, const float* __restrict__ b1f,
    const u16* __restrict__ fragW, const float* __restrict__ bqkv,
    const float* __restrict__ fb, const u16* __restrict__ woF,
    const float* __restrict__ bo, const float* __restrict__ g2,
    const float* __restrict__ b2v,
    float* __restrict__ hs_out, u16* __restrict__ y2)
{
  __shared__ __align__(16) u16 lds[75776];   // 151552 B
  int tid = threadIdx.x, lane = tid & 63, wid = tid >> 6;
  int lg = lane >> 4, lr = lane & 15;
  int h = wid >> 1, s = wid & 1;
  int gw = blockIdx.x;
  int bi = gw >> 6, win = gw & 63, wh = win >> 3, wwi = win & 7;

  // ---- Phase 1: LN1 + cyclic-shift gather -> xb (chunk-XOR swizzled) ----
  {
    int t = wid*4 + (lane >> 4);           // token 0..63 (16 lanes/token)
    int j = lane & 15;                     // 16-channel slice
    int hh_ = (wh*8 + (t >> 3) + 4) & 63;
    int ww_ = (wwi*8 + (t & 7) + 4) & 63;
    const float4* row = (const float4*)(hidden + ((size_t)bi*4096 + hh_*64 + ww_)*256) + j*4;
    float4 v[4]; float sm = 0.f, sq = 0.f;
#pragma unroll
    for (int i=0;i<4;i++){
      v[i] = row[i];
      sm += v[i].x+v[i].y+v[i].z+v[i].w;
      sq += v[i].x*v[i].x+v[i].y*v[i].y+v[i].z*v[i].z+v[i].w*v[i].w;
    }
    sm += __shfl_xor(sm,1); sq += __shfl_xor(sq,1);
    sm += __shfl_xor(sm,2); sq += __shfl_xor(sq,2);
    sm += __shfl_xor(sm,4); sq += __shfl_xor(sq,4);
    sm += __shfl_xor(sm,8); sq += __shfl_xor(sq,8);
    float mean = sm*(1.f/256.f);
    float inv = rsqrtf(sq*(1.f/256.f) - mean*mean + 1e-5f);
    const float4* gg = (const float4*)g1 + j*4;
    const float4* bb = (const float4*)b1f + j*4;
#pragma unroll
    for (int i2=0;i2<2;i2++){
      float4 a0=v[2*i2], a1=v[2*i2+1];
      float4 g0=gg[2*i2], g1_=gg[2*i2+1];
      float4 b0=bb[2*i2], b1_=bb[2*i2+1];
      u16x8 pk;
      pk[0]=f2bf((a0.x-mean)*inv*g0.x+b0.x); pk[1]=f2bf((a0.y-mean)*inv*g0.y+b0.y);
      pk[2]=f2bf((a0.z-mean)*inv*g0.z+b0.z); pk[3]=f2bf((a0.w-mean)*inv*g0.w+b0.w);
      pk[4]=f2bf((a1.x-mean)*inv*g1_.x+b1_.x); pk[5]=f2bf((a1.y-mean)*inv*g1_.y+b1_.y);
      pk[6]=f2bf((a1.z-mean)*inv*g1_.z+b1_.z); pk[7]=f2bf((a1.w-mean)*inv*g1_.w+b1_.w);
      int c = (j*2 + i2) ^ (t & 7);
      *(u16x8*)(&lds[t*256 + c*8]) = pk;
    }
  }
  __syncthreads();

  // ---- Phase 2: mini-GEMM q/k/v for head h, token half s (fragW from L2) ----
  f32x4 qa[2][2]={}, ka[2][2]={}, va[2][2]={};
  __builtin_amdgcn_s_setprio(1);
#pragma unroll
  for (int ks=0; ks<8; ks++){
    bf16x8 af[2];
#pragma unroll
    for (int mi=0;mi<2;mi++){
      int tok = 32*s + mi*16 + lr;
      af[mi] = *(const bf16x8*)(&lds[tok*256 + (((ks*4+lg) ^ (tok&7))*8)]);
    }
    const u16* fq = fragW + ((((size_t)h)*8 + ks)*2)*512 + lane*8;
#pragma unroll
    for (int nj=0;nj<2;nj++){
      bf16x8 bq_ = *(const bf16x8*)(fq + nj*512);
      bf16x8 bk_ = *(const bf16x8*)(fq + 65536 + nj*512);
      bf16x8 bv_ = *(const bf16x8*)(fq + 131072 + nj*512);
#pragma unroll
      for (int mi=0;mi<2;mi++){
        qa[mi][nj] = MFMA_BF16(af[mi], bq_, qa[mi][nj], 0,0,0);
        ka[mi][nj] = MFMA_BF16(af[mi], bk_, ka[mi][nj], 0,0,0);
        va[mi][nj] = MFMA_BF16(af[mi], bv_, va[mi][nj], 0,0,0);
      }
    }
  }
  __builtin_amdgcn_s_setprio(0);

  // ---- Phase 3: q/k/v -> per-head arena (each wave writes its token half) ----
  u16* hb  = &lds[16384 + h*7424];
  u16* k_h = hb;                    // [64][40]
  u16* v_h = hb + 2560;             // [32 dims][72]
  u16* q_s = hb + 4864 + s*1280;    // [32][40]
  const float scale = 0.1767766952966369f; // 32^-0.5
#pragma unroll
  for (int mi=0;mi<2;mi++)
#pragma unroll
  for (int nj=0;nj<2;nj++){
    int dim = nj*16+lr;
    float bq_ = bqkv[h*32+dim], bk_ = bqkv[256+h*32+dim], bv_ = bqkv[512+h*32+dim];
#pragma unroll
    for (int r=0;r<4;r++){
      int tokl = mi*16+4*lg+r;            // local 0..31
      q_s[tokl*40+dim] = f2bf((qa[mi][nj][r]+bq_)*scale);
      k_h[(32*s+tokl)*40+dim] = f2bf(ka[mi][nj][r]+bk_);
    }
    ushort4 vp;
    vp.x = f2bf(va[mi][nj][0]+bv_); vp.y = f2bf(va[mi][nj][1]+bv_);
    vp.z = f2bf(va[mi][nj][2]+bv_); vp.w = f2bf(va[mi][nj][3]+bv_);
    *(ushort4*)(&v_h[dim*72 + 32*s + mi*16 + 4*lg]) = vp;
  }
  __syncthreads();   // k_h/v_h halves from both waves visible

  // ---- Phase 4: QK^T (32 q-rows x 64 k) + bias/mask + softmax ----
  bf16x8 qf[2], kf[4];
#pragma unroll
  for (int i=0;i<2;i++)
    qf[i] = *(const bf16x8*)(&q_s[(i*16+lr)*40 + 8*lg]);
#pragma unroll
  for (int i=0;i<4;i++)
    kf[i] = *(const bf16x8*)(&k_h[(i*16+lr)*40 + 8*lg]);
  f32x4 acc[2][4] = {};
#pragma unroll
  for (int mi=0;mi<2;mi++)
#pragma unroll
  for (int nj=0;nj<4;nj++)
    acc[mi][nj] = MFMA_BF16(qf[mi], kf[nj], acc[mi][nj], 0,0,0);

  int cls = ((wh==7) ? 2 : 0) | ((wwi==7) ? 1 : 0);
  const float4* fb4 = (const float4*)(fb + (((size_t)cls*8 + h) << 12));
#pragma unroll
  for (int mi=0;mi<2;mi++)
#pragma unroll
  for (int r=0;r<4;r++){
    int m = 32*s + mi*16 + 4*lg + r;
    float4 bv4 = fb4[m*16 + lr];
#pragma unroll
    for (int nj=0;nj<4;nj++)
      acc[mi][nj][r] += bv4[nj];
  }
#pragma unroll
  for (int mi=0;mi<2;mi++)
#pragma unroll
  for (int r=0;r<4;r++){
    float mx = fmaxf(fmaxf(acc[mi][0][r], acc[mi][1][r]), fmaxf(acc[mi][2][r], acc[mi][3][r]));
    for (int off=1; off<16; off<<=1) mx = fmaxf(mx, __shfl_xor(mx, off));
    float sum = 0.f;
#pragma unroll
    for (int nj=0;nj<4;nj++){ float e = __expf(acc[mi][nj][r]-mx); acc[mi][nj][r]=e; sum+=e; }
    for (int off=1; off<16; off<<=1) sum += __shfl_xor(sum, off);
    float inv = 1.f/sum;
#pragma unroll
    for (int nj=0;nj<4;nj++) acc[mi][nj][r] *= inv;
  }

  // P overwrites k/q regions read by partner's QK^T; also all phase-2 xb reads
  // must be done before the out-tile overwrites xb below -> block sync.
  __syncthreads();

  u16* P_s = s ? hb : (hb + 4864);   // [32][72], wave-private
#pragma unroll
  for (int mi=0;mi<2;mi++)
#pragma unroll
  for (int nj=0;nj<4;nj++)
#pragma unroll
  for (int r=0;r<4;r++)
    P_s[(mi*16+4*lg+r)*72 + nj*16 + lr] = f2bf(acc[mi][nj][r]);

  // ---- Phase 5: PV (own 32 rows x full V) ----
  f32x4 acc2[2][2] = {};
#pragma unroll
  for (int ks=0; ks<2; ks++){
    bf16x8 vf0 = *(const bf16x8*)(&v_h[(lr)*72 + ks*32 + 8*lg]);
    bf16x8 vf1 = *(const bf16x8*)(&v_h[(16+lr)*72 + ks*32 + 8*lg]);
#pragma unroll
    for (int mi=0;mi<2;mi++){
      bf16x8 pf = *(const bf16x8*)(&P_s[(mi*16+lr)*72 + ks*32 + 8*lg]);
      acc2[mi][0] = MFMA_BF16(pf, vf0, acc2[mi][0], 0,0,0);
      acc2[mi][1] = MFMA_BF16(pf, vf1, acc2[mi][1], 0,0,0);
    }
  }

  // ---- Phase 6: attn-out tile -> xb (same chunk-XOR swizzle) ----
#pragma unroll
  for (int mi=0;mi<2;mi++)
#pragma unroll
  for (int nt=0;nt<2;nt++)
#pragma unroll
  for (int r=0;r<4;r++){
    int row = 32*s + mi*16 + 4*lg + r;
    int chunk = (4*h + 2*nt + (lr>>3)) ^ (row & 7);
    lds[row*256 + chunk*8 + (lr&7)] = f2bf(acc2[mi][nt][r]);
  }
  __syncthreads();   // full 64x256 out tile visible; arenas now dead

  // ---- Phase 7: O-proj mini-GEMM: rows 32s..+31, cols 32h..+31, K=256 ----
  f32x4 po[2][2] = {};
  __builtin_amdgcn_s_setprio(1);
#pragma unroll
  for (int ks=0; ks<8; ks++){
    bf16x8 af2[2];
#pragma unroll
    for (int mi=0;mi<2;mi++){
      int row = 32*s + mi*16 + lr;
      af2[mi] = *(const bf16x8*)(&lds[row*256 + (((ks*4+lg) ^ (row&7))*8)]);
    }
#pragma unroll
    for (int nj=0;nj<2;nj++){
      bf16x8 bw = *(const bf16x8*)(woF + (((size_t)(2*h+nj))*8 + ks)*512 + lane*8);
#pragma unroll
      for (int mi=0;mi<2;mi++)
        po[mi][nj] = MFMA_BF16(af2[mi], bw, po[mi][nj], 0,0,0);
    }
  }
  __builtin_amdgcn_s_setprio(0);

  // ---- Phase 8: +bo, window-reverse residual, hs -> d_out, LN2 partials ----
  float* part_s = (float*)&lds[16384];          // [64][8]
  float* part_q = (float*)&lds[16384 + 1024];   // [64][8]
  float bov[2], g2v[2], b2vv[2];
#pragma unroll
  for (int nj=0;nj<2;nj++){
    int n = 32*h + nj*16 + lr;
    bov[nj] = bo[n]; g2v[nj] = g2[n]; b2vv[nj] = b2v[n];
  }
#pragma unroll
  for (int mi=0;mi<2;mi++)
#pragma unroll
  for (int r=0;r<4;r++){
    int p = 32*s + mi*16 + 4*lg + r;       // row in window
    int hh_ = (wh*8 + (p >> 3) + 4) & 63;
    int ww_ = (wwi*8 + (p & 7) + 4) & 63;
    size_t base = ((size_t)bi*4096 + hh_*64 + ww_)*256;
    float ls = 0.f, lq = 0.f;
#pragma unroll
    for (int nj=0;nj<2;nj++){
      int n = 32*h + nj*16 + lr;
      float v = po[mi][nj][r] + bov[nj] + hidden[base + n];
      hs_out[base + n] = v;
      po[mi][nj][r] = v;
      ls += v; lq += v*v;
    }
    ls += __shfl_xor(ls,1); lq += __shfl_xor(lq,1);
    ls += __shfl_xor(ls,2); lq += __shfl_xor(lq,2);
    ls += __shfl_xor(ls,4); lq += __shfl_xor(lq,4);
    ls += __shfl_xor(ls,8); lq += __shfl_xor(lq,8);
    if (lr == 0){ part_s[p*8 + h] = ls; part_q[p*8 + h] = lq; }
  }
  __syncthreads();

  // ---- Phase 9: LN2 finalize -> y2 bf16 (token order) ----
#pragma unroll
  for (int mi=0;mi<2;mi++)
#pragma unroll
  for (int r=0;r<4;r++){
    int p = 32*s + mi*16 + 4*lg + r;
    int hh_ = (wh*8 + (p >> 3) + 4) & 63;
    int ww_ = (wwi*8 + (p & 7) + 4) & 63;
    size_t base = ((size_t)bi*4096 + hh_*64 + ww_)*256;
    float sum = 0.f, sqq = 0.f;
#pragma unroll
    for (int hh2=0; hh2<8; hh2++){ sum += part_s[p*8 + hh2]; sqq += part_q[p*8 + hh2]; }
    float mean = sum*(1.f/256.f);
    float inv = rsqrtf(sqq*(1.f/256.f) - mean*mean + 1e-5f);
#pragma unroll
    for (int nj=0;nj<2;nj++){
      int n = 32*h + nj*16 + lr;
      y2[base + n] = f2bf((po[mi][nj][r]-mean)*inv*g2v[nj] + b2vv[nj]);
    }
  }
}

// ======== FUSED MLP: out = hs + GELU(y2 @ w1 + b1) @ w2 + b2, K-split over d_ff ========
// 8 half-width slices (128 ff-cols), DOUBLE-BUFFERED xt (16KB each), ONE barrier
// per slice: {FC1(c); GELU-write->xt[c&1]; barrier; FC2(c)}. Leading waves'
// FC1/GELU overlap trailing waves' FC2 MFMA (disjoint xt buffers; skew bounded
// by the single barrier). erff GELU (exp/rcp TRANS-pipe forms regressed: R17/R19).
__global__ __launch_bounds__(512) void k_mlp(const u16* __restrict__ y2ln,
    const u16* __restrict__ w1F, const u16* __restrict__ w2F,
    const float* __restrict__ b1, const float* __restrict__ b2,
    float* __restrict__ io)
{
  __shared__ __align__(16) u16 lds[32768];   // xb [0,16384) + xt0 [16384,24576) + xt1 [24576,32768)
  int tid = threadIdx.x, lane = tid & 63, wid = tid >> 6;
  int lg = lane >> 4, lr = lane & 15;
  int wr_ = wid >> 2, wc_ = wid & 3;
  int m0 = blockIdx.x*64;

  // stage x = y2ln rows m0..+64 into xb, chunk-XOR swizzled via pre-swizzled source
  {
    int row_lo = tid >> 5;           // 0..15
    int ch = tid & 31;               // 16B chunk within 512B row
#pragma unroll
    for (int i=0;i<4;i++){
      int row = i*16 + row_lo;
      int sch = ch ^ (row & 7);
      gll16(y2ln + (size_t)(m0+row)*256 + sch*8, &lds[i*4096 + tid*8]);
    }
  }
  asm volatile("s_waitcnt vmcnt(0)" ::: "memory");
  __syncthreads();

  f32x4 accY[2][4] = {};
  float b2v[4];
#pragma unroll
  for (int nj=0;nj<4;nj++) b2v[nj] = b2[wc_*64 + nj*16 + lr];

#pragma unroll
  for (int c = 0; c < 8; c++){
    u16* xt = &lds[16384 + (c & 1)*8192];   // [64][128] swizzled
    // ---- FC1: t_c[64][wid*16..+16] = x @ w1[:, c*128 + wid*16 ..], K=256 ----
    f32x4 acc1[4] = {};
    __builtin_amdgcn_s_setprio(1);
#pragma unroll
    for (int ks=0; ks<8; ks++){
      bf16x8 af[4];
#pragma unroll
      for (int mi=0;mi<4;mi++){
        int row = mi*16 + lr;
        af[mi] = *(const bf16x8*)(&lds[row*256 + (((ks*4+lg) ^ (row&7))<<3)]);
      }
      bf16x8 bw = *(const bf16x8*)(w1F + ((((size_t)(c*8 + wid))*8 + ks)<<9) + lane*8);
#pragma unroll
      for (int mi=0;mi<4;mi++)
        acc1[mi] = MFMA_BF16(af[mi], bw, acc1[mi], 0,0,0);
    }
    __builtin_amdgcn_s_setprio(0);
    // GELU + write t (16 chunks/row, chunk ^= row&7)
    {
      float b1v = b1[c*128 + wid*16 + lr];
#pragma unroll
      for (int mi=0;mi<4;mi++)
#pragma unroll
      for (int r=0;r<4;r++){
        int row = mi*16 + 4*lg + r;
        int col = wid*16 + lr;
        float v = acc1[mi][r] + b1v;
        float gv = 0.5f*v*(1.f + erff(v*0.70710678118654752f));
        xt[row*128 + ((((col>>3) ^ (row&7))<<3) | (col&7))] = f2bf(gv);
      }
    }
    __syncthreads();   // t_c visible; laggards' FC2(c-1) read the OTHER buffer
    // ---- FC2: accY += t_c[32wr_..+32][0..128] @ w2[c*128..+128][64wc_..+64] ----
    __builtin_amdgcn_s_setprio(1);
#pragma unroll
    for (int ks=0; ks<4; ks++){
      bf16x8 af2[2];
#pragma unroll
      for (int mi=0;mi<2;mi++){
        int row = wr_*32 + mi*16 + lr;
        af2[mi] = *(const bf16x8*)(&xt[row*128 + (((ks*4+lg) ^ (row&7))<<3)]);
      }
#pragma unroll
      for (int nj=0;nj<4;nj++){
        bf16x8 bw = *(const bf16x8*)(w2F + ((((size_t)(wc_*4 + nj))*32 + c*4 + ks)<<9) + lane*8);
#pragma unroll
        for (int mi=0;mi<2;mi++)
          accY[mi][nj] = MFMA_BF16(af2[mi], bw, accY[mi][nj], 0,0,0);
      }
    }
    __builtin_amdgcn_s_setprio(0);
  }

  // ---- epilogue: out = accY + b2 + hs (in place, fp32) ----
#pragma unroll
  for (int mi=0;mi<2;mi++)
#pragma unroll
  for (int nj=0;nj<4;nj++)
#pragma unroll
  for (int r=0;r<4;r++){
    int m = m0 + wr_*32 + mi*16 + 4*lg + r;
    int n = wc_*64 + nj*16 + lr;
    io[(size_t)m*256 + n] = accY[mi][nj][r] + b2v[nj] + io[(size_t)m*256 + n];
  }
}

extern "C" void kernel_launch(void* const* d_in, const int* in_sizes, int n_in,
                              void* d_out, int out_size, void* d_ws, size_t ws_size,
                              hipStream_t stream){
  const float* hidden = (const float*)d_in[0];
  const float* ln1g = (const float*)d_in[1];
  const float* ln1b = (const float*)d_in[2];
  const float* wq   = (const float*)d_in[3];
  const float* bq   = (const float*)d_in[4];
  const float* wk   = (const float*)d_in[5];
  const float* bk   = (const float*)d_in[6];
  const float* wv   = (const float*)d_in[7];
  const float* bv   = (const float*)d_in[8];
  const float* btab = (const float*)d_in[9];
  const float* wo   = (const float*)d_in[10];
  const float* bo   = (const float*)d_in[11];
  const float* ln2g = (const float*)d_in[12];
  const float* ln2b = (const float*)d_in[13];
  const float* w1   = (const float*)d_in[14];
  const float* b1   = (const float*)d_in[15];
  const float* w2   = (const float*)d_in[16];
  const float* b2   = (const float*)d_in[17];
  float* out = (float*)d_out;

  char* ws = (char*)d_ws;
  const size_t MB = 1ull << 20;
  u16* y2ln  = (u16*)(ws + 192*MB);      // LN2 out (64MB)
  u16* fragW = (u16*)(ws + 256*MB);      // QKV weights, fragment-major (384KB)
  u16* woF   = fragW + 196608;           // 16*8*512  = 65536 u16
  u16* w1F   = woF + 65536;              // 64*8*512  = 262144 u16
  u16* w2F   = w1F + 262144;             // 16*32*512 = 262144 u16
  float* bqkv = (float*)(w2F + 262144);
  float* fbias = bqkv + 1024;            // 4*8*64*64 fp32 = 512KB

  // weight prep
  k_fragw<<<768, 256, 0, stream>>>(wq, wk, wv, fragW);
  k_wfrag<<<256, 256, 0, stream>>>(wo, woF, 256, 256);
  k_wfrag<<<1024,256, 0, stream>>>(w1, w1F, 256, 1024);
  k_wfrag<<<1024,256, 0, stream>>>(w2, w2F, 1024, 256);
  k_concat_bias<<<1, 768, 0, stream>>>(bq, bk, bv, bqkv);
  k_bias<<<512, 256, 0, stream>>>(btab, fbias);

  // fused LN1 + shift + QKV + attention + O-proj + residual -> hs (d_out), LN2 -> y2ln
  k_fattn<<<2048, 1024, 0, stream>>>(hidden, ln1g, ln1b, fragW, bqkv, fbias,
                                     woF, bo, ln2g, ln2b, out, y2ln);
  // fused MLP (FC1 + GELU + FC2 + residual), y1 stays in LDS, xt double-buffered
  k_mlp<<<2048, 512, 0, stream>>>(y2ln, w1F, w2F, b1, b2, out);
}